// Round 11
// baseline (1016.856 us; speedup 1.0000x reference)
//
#include <hip/hip_runtime.h>

#define N_ENEMY 4000000
#define N_GUN   1000000
#define N_EDGES 16000000
#define OUTD    8

// ---- thirds pipeline config ----
#define QMAX  5333334            // max edges per pass (3 passes)
#define ST    4096               // sscatter tile
#define SEPT  16                 // ST/256
#define NT    1303               // ceil(QMAX/ST)
#define SB    1024               // src windows (4096 enemies = 32KB bf16 window)
#define SSH   12
#define RT    4096               // dscatter chunk
#define REPT  16                 // RT/256
#define TPB   3                  // chunks per src window (cap 12288 vs mean 5461)
#define DG    (SB*TPB)           // 3072
#define NDB   1024               // dst buckets (977 guns each)
#define GPB   977

// exact floor(dst/977) for dst <= 1M
__device__ __forceinline__ unsigned int bucket_of(unsigned int dst) {
    return (unsigned int)(((unsigned long long)dst * 1125395730ull) >> 40);
}
__device__ __forceinline__ unsigned int rne_bf16(unsigned int u) {
    return (u + 0x7FFFu + ((u >> 16) & 1u)) >> 16;
}

// ---- Fold W_l@W_fc (4x8), W_r@W_fc (8), b_l@W_fc + b_fc (8) into P[48] ----
__global__ void prep_params(const float* __restrict__ W_l, const float* __restrict__ b_l,
                            const float* __restrict__ W_r, const float* __restrict__ W_fc,
                            const float* __restrict__ b_fc, float* __restrict__ P) {
    int o = threadIdx.x;
    if (o < OUTD) {
        float a0 = 0.f, a1 = 0.f, a2 = 0.f, a3 = 0.f, r = 0.f, c = 0.f;
        for (int h = 0; h < 64; ++h) {
            float w = W_fc[h * OUTD + o];
            a0 += W_l[0 * 64 + h] * w;
            a1 += W_l[1 * 64 + h] * w;
            a2 += W_l[2 * 64 + h] * w;
            a3 += W_l[3 * 64 + h] * w;
            r  += W_r[h] * w;
            c  += b_l[h] * w;
        }
        P[0 * OUTD + o] = a0;
        P[1 * OUTD + o] = a1;
        P[2 * OUTD + o] = a2;
        P[3 * OUTD + o] = a3;
        P[4 * OUTD + o] = r;
        P[5 * OUTD + o] = c + b_fc[o];
    }
}

// ---- per-tile src-window histogram ----
__global__ void shist_t(const int* __restrict__ qs, int qlen,
                        unsigned short* __restrict__ stileh) {
    __shared__ unsigned int lh[SB];
    int t = threadIdx.x;
    for (int i = t; i < SB; i += 256) lh[i] = 0;
    __syncthreads();
    int base = blockIdx.x * ST;
    int n = qlen - base; if (n > ST) n = ST; if (n < 0) n = 0;
    for (int i = t; i < n; i += 256)
        atomicAdd(&lh[((unsigned)qs[base + i]) >> SSH], 1u);
    __syncthreads();
    unsigned short* row = stileh + (size_t)blockIdx.x * SB;
    for (int i = t; i < SB; i += 256) row[i] = (unsigned short)lh[i];
}

// ---- per-bucket exclusive prefix over tiles (in-place) + totals ----
template<int K>
__global__ __launch_bounds__(256)
void tile_scanT(unsigned short* __restrict__ tileh, unsigned int* __restrict__ tot,
                int nbk, int ntile) {
    __shared__ unsigned int part[256][17];
    int t = threadIdx.x;
    int b0 = blockIdx.x * 16;
    unsigned int loc[16];
#pragma unroll
    for (int j = 0; j < 16; ++j) loc[j] = 0;
    for (int k = 0; k < K; ++k) {
        int tile = t * K + k;
        if (tile < ntile) {
            const unsigned short* row = tileh + (size_t)tile * nbk + b0;
#pragma unroll
            for (int j = 0; j < 16; ++j) loc[j] += row[j];
        }
    }
#pragma unroll
    for (int j = 0; j < 16; ++j) part[t][j] = loc[j];
    __syncthreads();
    if (t < 16) {
        unsigned int acc = 0;
        for (int i = 0; i < 256; ++i) {
            unsigned int v = part[i][t];
            part[i][t] = acc;
            acc += v;
        }
        tot[b0 + t] = acc;
    }
    __syncthreads();
    unsigned int run[16];
#pragma unroll
    for (int j = 0; j < 16; ++j) run[j] = part[t][j];
    for (int k = 0; k < K; ++k) {
        int tile = t * K + k;
        if (tile < ntile) {
            unsigned short* row = tileh + (size_t)tile * nbk + b0;
#pragma unroll
            for (int j = 0; j < 16; ++j) {
                unsigned int c = row[j];
                row[j] = (unsigned short)run[j];
                run[j] += c;
            }
        }
    }
}

__global__ void scan1024(const unsigned int* __restrict__ tot, unsigned int* __restrict__ offs) {
    __shared__ unsigned int tmp[1024];
    int t = threadIdx.x;
    unsigned int v0 = tot[t];
    tmp[t] = v0;
    __syncthreads();
    for (int d = 1; d < 1024; d <<= 1) {
        unsigned int v = (t >= d) ? tmp[t - d] : 0u;
        __syncthreads();
        tmp[t] += v;
        __syncthreads();
    }
    offs[t] = tmp[t] - v0;
    if (t == 1023) offs[1024] = tmp[t];
}

// ---- tile-sort by src window; rec = (src_local<<20)|dst; zero global atomics ----
__global__ __launch_bounds__(256)
void sscatter_t(const int* __restrict__ qs, const int* __restrict__ qd, int qlen,
                const unsigned int* __restrict__ sOffs,
                const unsigned short* __restrict__ stileh,
                unsigned int* __restrict__ rec) {
    __shared__ unsigned int cnt[SB];
    __shared__ unsigned int base_[SB];
    __shared__ unsigned short bOf[ST];
    __shared__ unsigned int sortR[ST];
    __shared__ unsigned int partial[256];
    int t = threadIdx.x;
    int tile = blockIdx.x;
    int lt = tile * ST;
    int n = qlen - lt; if (n > ST) n = ST; if (n < 0) n = 0;

    for (int i = t; i < SB; i += 256) cnt[i] = 0;
    __syncthreads();

    unsigned int w[SEPT], br[SEPT];
#pragma unroll
    for (int k = 0; k < SEPT; ++k) {
        int idx = k * 256 + t;
        if (idx < n) {
            unsigned int s = (unsigned int)qs[lt + idx];
            unsigned int d = (unsigned int)qd[lt + idx];
            unsigned int b = s >> SSH;
            unsigned int r = atomicAdd(&cnt[b], 1u);
            w[k]  = ((s & 4095u) << 20) | d;
            br[k] = (b << 13) | r;
        } else br[k] = 0xFFFFFFFFu;
    }
    __syncthreads();

    unsigned int loc[4];
    unsigned int acc = 0;
#pragma unroll
    for (int j = 0; j < 4; ++j) {
        int b = t * 4 + j;
        unsigned int c = cnt[b];
        loc[j] = acc; acc += c;
    }
    partial[t] = acc;
    __syncthreads();
    for (int d = 1; d < 256; d <<= 1) {
        unsigned int v = (t >= d) ? partial[t - d] : 0u;
        __syncthreads();
        partial[t] += v;
        __syncthreads();
    }
    unsigned int excl = (t > 0) ? partial[t - 1] : 0u;
#pragma unroll
    for (int j = 0; j < 4; ++j) base_[t * 4 + j] = excl + loc[j];
    __syncthreads();

#pragma unroll
    for (int j = 0; j < 4; ++j) {
        int b = t * 4 + j;
        unsigned int bs = base_[b], c = cnt[b];
        for (unsigned int p = bs; p < bs + c; ++p) bOf[p] = (unsigned short)b;
    }
    __syncthreads();

#pragma unroll
    for (int k = 0; k < SEPT; ++k) {
        if (br[k] != 0xFFFFFFFFu) {
            unsigned int b = br[k] >> 13, r = br[k] & 8191u;
            sortR[base_[b] + r] = w[k];
        }
    }
    __syncthreads();

    const unsigned short* trow = stileh + (size_t)tile * SB;
    for (int p = t; p < n; p += 256) {
        unsigned int b = bOf[p];
        rec[sOffs[b] + (unsigned int)trow[b] + ((unsigned int)p - base_[b])] = sortR[p];
    }
}

// ---- per-(window,chunk) dst-bucket histogram over src-sorted rec ----
__global__ void dhist_t(const unsigned int* __restrict__ rec,
                        const unsigned int* __restrict__ sOffs,
                        unsigned short* __restrict__ dtileh) {
    __shared__ unsigned int lh[NDB];
    int t = threadIdx.x;
    for (int i = t; i < NDB; i += 256) lh[i] = 0;
    __syncthreads();
    int sb = blockIdx.x / TPB, chunk = blockIdx.x % TPB;
    unsigned int segE = sOffs[sb + 1];
    unsigned int st = sOffs[sb] + (unsigned int)chunk * RT;
    int n = (st < segE) ? (int)((segE - st < RT) ? (segE - st) : RT) : 0;
    for (int i = t; i < n; i += 256)
        atomicAdd(&lh[bucket_of(rec[st + i] & 0xFFFFFu)], 1u);
    __syncthreads();
    unsigned short* row = dtileh + (size_t)blockIdx.x * NDB;
    for (int i = t; i < NDB; i += 256) row[i] = (unsigned short)lh[i];
}

// ---- fused: f32 window -> bf16 LDS, gather from LDS, dst-bucket sort -> (val,g) ----
__global__ __launch_bounds__(256)
void dscatter_t(const unsigned int* __restrict__ rec, const uint4* __restrict__ xe,
                const unsigned int* __restrict__ sOffs, const unsigned int* __restrict__ dOffs,
                const unsigned short* __restrict__ dtileh,
                unsigned long long* __restrict__ val, unsigned short* __restrict__ gArr) {
    __shared__ unsigned long long win[4096];   // 32KB bf16x4 window
    __shared__ unsigned int cnt[NDB];
    __shared__ unsigned int base_[NDB];
    __shared__ unsigned short bOf[RT];
    __shared__ unsigned int sortW[RT];
    __shared__ unsigned int partial[256];
    int t = threadIdx.x;
    int sb = blockIdx.x;

    for (int j = t; j < 4096; j += 256) {
        unsigned int idx = ((unsigned int)sb << SSH) + j;
        if (idx < N_ENEMY) {
            uint4 v = xe[idx];
            unsigned long long lo = (unsigned long long)(rne_bf16(v.x) | (rne_bf16(v.y) << 16));
            unsigned long long hi = (unsigned long long)(rne_bf16(v.z) | (rne_bf16(v.w) << 16));
            win[j] = lo | (hi << 32);
        }
    }
    unsigned int segS = sOffs[sb], segE = sOffs[sb + 1];

    for (int chunk = 0; chunk < TPB; ++chunk) {
        unsigned int st = segS + (unsigned int)chunk * RT;
        if (st >= segE) break;
        int n = (int)((segE - st < RT) ? (segE - st) : RT);

        for (int i = t; i < NDB; i += 256) cnt[i] = 0;
        __syncthreads();

        unsigned int w[REPT], br[REPT];
#pragma unroll
        for (int k = 0; k < REPT; ++k) {
            int idx = k * 256 + t;
            if (idx < n) {
                unsigned int r = rec[st + idx];
                unsigned int dst = r & 0xFFFFFu;
                unsigned int db = bucket_of(dst);
                unsigned int g = dst - db * GPB;
                unsigned int rk = atomicAdd(&cnt[db], 1u);
                w[k]  = ((r >> 20) << 10) | g;
                br[k] = (db << 13) | rk;
            } else br[k] = 0xFFFFFFFFu;
        }
        __syncthreads();

        unsigned int loc[4];
        unsigned int acc = 0;
#pragma unroll
        for (int j = 0; j < 4; ++j) {
            int b = t * 4 + j;
            unsigned int c = cnt[b];
            loc[j] = acc; acc += c;
        }
        partial[t] = acc;
        __syncthreads();
        for (int d = 1; d < 256; d <<= 1) {
            unsigned int v = (t >= d) ? partial[t - d] : 0u;
            __syncthreads();
            partial[t] += v;
            __syncthreads();
        }
        unsigned int excl = (t > 0) ? partial[t - 1] : 0u;
#pragma unroll
        for (int j = 0; j < 4; ++j) base_[t * 4 + j] = excl + loc[j];
        __syncthreads();

#pragma unroll
        for (int j = 0; j < 4; ++j) {
            int b = t * 4 + j;
            unsigned int bs = base_[b], c = cnt[b];
            for (unsigned int p = bs; p < bs + c; ++p) bOf[p] = (unsigned short)b;
        }
        __syncthreads();

#pragma unroll
        for (int k = 0; k < REPT; ++k) {
            if (br[k] != 0xFFFFFFFFu) {
                unsigned int b = br[k] >> 13, rk = br[k] & 8191u;
                sortW[base_[b] + rk] = w[k];
            }
        }
        __syncthreads();

        const unsigned short* drow = dtileh + (size_t)(sb * TPB + chunk) * NDB;
        for (int p = t; p < n; p += 256) {
            unsigned int b = bOf[p];
            unsigned int ww = sortW[p];
            unsigned int pos = dOffs[b] + (unsigned int)drow[b] + ((unsigned int)p - base_[b]);
            val[pos] = win[ww >> 10];
            gArr[pos] = (unsigned short)(ww & 1023u);
        }
        __syncthreads();
    }
}

// ---- aggregate: coalesced streams, 4-deep ILP, LDS accum, bf16-packed global RMW ----
__global__ __launch_bounds__(256)
void agg_t(const unsigned int* __restrict__ dOffs,
           const unsigned long long* __restrict__ val,
           const unsigned short* __restrict__ gArr,
           unsigned long long* __restrict__ sumP, unsigned short* __restrict__ cntA) {
    __shared__ float s0[GPB], s1[GPB], s2[GPB], s3[GPB];
    __shared__ unsigned int cc[GPB];
    int t = threadIdx.x;
    for (int i = t; i < GPB; i += 256) {
        s0[i] = 0.f; s1[i] = 0.f; s2[i] = 0.f; s3[i] = 0.f; cc[i] = 0u;
    }
    __syncthreads();
    unsigned int b = blockIdx.x;
    unsigned int st = dOffs[b], en = dOffs[b + 1];

#define ACC(v, g) { \
    unsigned int lo = (unsigned int)(v), hi = (unsigned int)((v) >> 32); \
    atomicAdd(&s0[g], __uint_as_float(lo << 16)); \
    atomicAdd(&s1[g], __uint_as_float(lo & 0xffff0000u)); \
    atomicAdd(&s2[g], __uint_as_float(hi << 16)); \
    atomicAdd(&s3[g], __uint_as_float(hi & 0xffff0000u)); \
    atomicAdd(&cc[g], 1u); }

    unsigned int i = st + (unsigned int)t;
    for (; i + 768 < en; i += 1024) {
        unsigned long long v0 = val[i];
        unsigned long long v1 = val[i + 256];
        unsigned long long v2 = val[i + 512];
        unsigned long long v3 = val[i + 768];
        unsigned int g0 = gArr[i], g1 = gArr[i + 256], g2 = gArr[i + 512], g3 = gArr[i + 768];
        ACC(v0, g0); ACC(v1, g1); ACC(v2, g2); ACC(v3, g3);
    }
    for (; i < en; i += 256) {
        unsigned long long v0 = val[i];
        unsigned int g0 = gArr[i];
        ACC(v0, g0);
    }
#undef ACC
    __syncthreads();

    for (int g = t; g < GPB; g += 256) {
        unsigned int G = b * GPB + (unsigned int)g;
        if (G >= N_GUN) continue;
        unsigned long long old = sumP[G];
        float o0 = __uint_as_float(((unsigned int)old & 0xffffu) << 16);
        float o1 = __uint_as_float((unsigned int)old & 0xffff0000u);
        float o2 = __uint_as_float(((unsigned int)(old >> 32) & 0xffffu) << 16);
        float o3 = __uint_as_float((unsigned int)(old >> 32) & 0xffff0000u);
        o0 += s0[g]; o1 += s1[g]; o2 += s2[g]; o3 += s3[g];
        unsigned long long lo = (unsigned long long)(rne_bf16(__float_as_uint(o0)) |
                                                    (rne_bf16(__float_as_uint(o1)) << 16));
        unsigned long long hi = (unsigned long long)(rne_bf16(__float_as_uint(o2)) |
                                                    (rne_bf16(__float_as_uint(o3)) << 16));
        sumP[G] = lo | (hi << 32);
        cntA[G] = (unsigned short)(cntA[G] + cc[g]);
    }
}

// ---- epilogue ----
__global__ void gun_final(const unsigned long long* __restrict__ sumP,
                          const unsigned short* __restrict__ cntA,
                          const float* __restrict__ xg, const float* __restrict__ P,
                          float* __restrict__ out) {
    __shared__ float sP[48];
    if (threadIdx.x < 48) sP[threadIdx.x] = P[threadIdx.x];
    __syncthreads();
    int g = blockIdx.x * blockDim.x + threadIdx.x;
    if (g >= N_GUN) return;
    unsigned long long sp = sumP[g];
    float cnt = (float)cntA[g];
    float m0 = __uint_as_float(((unsigned int)sp & 0xffffu) << 16);
    float m1 = __uint_as_float((unsigned int)sp & 0xffff0000u);
    float m2 = __uint_as_float(((unsigned int)(sp >> 32) & 0xffffu) << 16);
    float m3 = __uint_as_float((unsigned int)(sp >> 32) & 0xffff0000u);
    float inv = 1.0f / fmaxf(cnt, 1.0f);
    m0 *= inv; m1 *= inv; m2 *= inv; m3 *= inv;
    float xv = xg[g];
    float res[OUTD];
#pragma unroll
    for (int o = 0; o < OUTD; ++o) {
        res[o] = m0 * sP[o] + m1 * sP[8 + o] + m2 * sP[16 + o] + m3 * sP[24 + o]
               + xv * sP[32 + o] + sP[40 + o];
    }
    float4* op = (float4*)(out + (size_t)g * OUTD);
    op[0] = make_float4(res[0], res[1], res[2], res[3]);
    op[1] = make_float4(res[4], res[5], res[6], res[7]);
}

// ================= atomic fallback (tiny ws) =================================
__global__ void edge_kernel(const int4* __restrict__ esrc4, const int4* __restrict__ edst4,
                            const float4* __restrict__ xe, float* __restrict__ summed,
                            float* __restrict__ counts) {
    int t = blockIdx.x * blockDim.x + threadIdx.x;
    if (t >= N_EDGES / 4) return;
    int4 s4 = esrc4[t];
    int4 d4 = edst4[t];
    int ss[4] = { s4.x, s4.y, s4.z, s4.w };
    int dd[4] = { d4.x, d4.y, d4.z, d4.w };
#pragma unroll
    for (int k = 0; k < 4; ++k) {
        float4 m = xe[ss[k]];
        float* basep = summed + (size_t)dd[k] * 4;
        atomicAdd(basep + 0, m.x);
        atomicAdd(basep + 1, m.y);
        atomicAdd(basep + 2, m.z);
        atomicAdd(basep + 3, m.w);
        atomicAdd(counts + dd[k], 1.0f);
    }
}

__global__ void gun_kernel(const float4* __restrict__ summed, const float* __restrict__ counts,
                           const float* __restrict__ xg, const float* __restrict__ P,
                           float* __restrict__ out) {
    __shared__ float sP[48];
    if (threadIdx.x < 48) sP[threadIdx.x] = P[threadIdx.x];
    __syncthreads();
    int g = blockIdx.x * blockDim.x + threadIdx.x;
    if (g >= N_GUN) return;
    float4 s = summed[g];
    float cnt = counts[g];
    float inv = 1.0f / fmaxf(cnt, 1.0f);
    float m0 = s.x * inv, m1 = s.y * inv, m2 = s.z * inv, m3 = s.w * inv;
    float xv = xg[g];
    float res[OUTD];
#pragma unroll
    for (int o = 0; o < OUTD; ++o) {
        res[o] = m0 * sP[o] + m1 * sP[8 + o] + m2 * sP[16 + o] + m3 * sP[24 + o]
               + xv * sP[32 + o] + sP[40 + o];
    }
    float4* op = (float4*)(out + (size_t)g * OUTD);
    op[0] = make_float4(res[0], res[1], res[2], res[3]);
    op[1] = make_float4(res[4], res[5], res[6], res[7]);
}

extern "C" void kernel_launch(void* const* d_in, const int* in_sizes, int n_in,
                              void* d_out, int out_size, void* d_ws, size_t ws_size,
                              hipStream_t stream) {
    const float* x_enemy = (const float*)d_in[0];
    const float* x_gun   = (const float*)d_in[1];
    const int*   esrc    = (const int*)d_in[2];
    const int*   edst    = (const int*)d_in[3];
    const float* W_l     = (const float*)d_in[4];
    const float* b_l     = (const float*)d_in[5];
    const float* W_r     = (const float*)d_in[6];
    const float* W_fc    = (const float*)d_in[7];
    const float* b_fc    = (const float*)d_in[8];
    float* out = (float*)d_out;

    // ws layout (u32 units) — 93.64 MB total (fits the proven 96.08 MB budget)
    const size_t REC_OFF    = 0;                                   // QMAX
    const size_t VAL_OFF    = REC_OFF + (size_t)QMAX;              // 2*QMAX (u64)
    const size_t G_OFF      = VAL_OFF + (size_t)QMAX * 2;          // QMAX/2 (u16)
    const size_t SUMP_OFF   = G_OFF + ((size_t)QMAX + 1) / 2;      // 2M (u64[1M])
    const size_t CNTA_OFF   = SUMP_OFF + (size_t)N_GUN * 2;        // 500K (u16[1M])
    const size_t STILEH_OFF = CNTA_OFF + (size_t)N_GUN / 2;        // u16[NT*SB]
    const size_t DTILEH_OFF = STILEH_OFF + ((size_t)NT * SB + 1) / 2;
    const size_t STOT_OFF   = DTILEH_OFF + ((size_t)DG * NDB + 1) / 2;
    const size_t SOFFS_OFF  = STOT_OFF + SB;                       // SB+1
    const size_t DTOT_OFF   = SOFFS_OFF + SB + 1;                  // NDB
    const size_t DOFFS_OFF  = DTOT_OFF + NDB;                      // NDB+1
    const size_t P_OFF      = DOFFS_OFF + NDB + 1;                 // 48
    const size_t NEEDED_T   = (P_OFF + 64) * sizeof(unsigned int);

    if (ws_size >= NEEDED_T) {
        unsigned int*       ws     = (unsigned int*)d_ws;
        unsigned int*       rec    = ws + REC_OFF;
        unsigned long long* val    = (unsigned long long*)(ws + VAL_OFF);
        unsigned short*     gArr   = (unsigned short*)(ws + G_OFF);
        unsigned long long* sumP   = (unsigned long long*)(ws + SUMP_OFF);
        unsigned short*     cntA   = (unsigned short*)(ws + CNTA_OFF);
        unsigned short*     stileh = (unsigned short*)(ws + STILEH_OFF);
        unsigned short*     dtileh = (unsigned short*)(ws + DTILEH_OFF);
        unsigned int*       stot   = ws + STOT_OFF;
        unsigned int*       sOffs  = ws + SOFFS_OFF;
        unsigned int*       dtot   = ws + DTOT_OFF;
        unsigned int*       dOffs  = ws + DOFFS_OFF;
        float*              P      = (float*)(ws + P_OFF);

        // zero sumP (8MB) + cntA (2MB) — contiguous
        hipMemsetAsync(ws + SUMP_OFF, 0, (size_t)N_GUN * 10, stream);
        prep_params<<<1, 64, 0, stream>>>(W_l, b_l, W_r, W_fc, b_fc, P);

        const int qstart[4] = { 0, 5333334, 10666667, 16000000 };
        for (int q = 0; q < 3; ++q) {
            const int* qs = esrc + qstart[q];
            const int* qd = edst + qstart[q];
            int qlen = qstart[q + 1] - qstart[q];
            shist_t<<<NT, 256, 0, stream>>>(qs, qlen, stileh);
            tile_scanT<6><<<SB / 16, 256, 0, stream>>>(stileh, stot, SB, NT);
            scan1024<<<1, 1024, 0, stream>>>(stot, sOffs);
            sscatter_t<<<NT, 256, 0, stream>>>(qs, qd, qlen, sOffs, stileh, rec);
            dhist_t<<<DG, 256, 0, stream>>>(rec, sOffs, dtileh);
            tile_scanT<12><<<NDB / 16, 256, 0, stream>>>(dtileh, dtot, NDB, DG);
            scan1024<<<1, 1024, 0, stream>>>(dtot, dOffs);
            dscatter_t<<<SB, 256, 0, stream>>>(rec, (const uint4*)x_enemy, sOffs, dOffs,
                                               dtileh, val, gArr);
            agg_t<<<NDB, 256, 0, stream>>>(dOffs, val, gArr, sumP, cntA);
        }
        gun_final<<<(N_GUN + 255) / 256, 256, 0, stream>>>(sumP, cntA, x_gun, P, out);
    } else {
        float* summed = (float*)d_ws;
        float* counts = summed + (size_t)N_GUN * 4;
        float* P      = counts + N_GUN;
        hipMemsetAsync(d_ws, 0, ((size_t)N_GUN * 5 + 48) * sizeof(float), stream);
        prep_params<<<1, 64, 0, stream>>>(W_l, b_l, W_r, W_fc, b_fc, P);
        int edge_threads = N_EDGES / 4;
        edge_kernel<<<(edge_threads + 255) / 256, 256, 0, stream>>>(
            (const int4*)esrc, (const int4*)edst, (const float4*)x_enemy, summed, counts);
        gun_kernel<<<(N_GUN + 255) / 256, 256, 0, stream>>>(
            (const float4*)summed, counts, x_gun, P, out);
    }
}

// Round 12
// 460.314 us; speedup vs baseline: 2.2090x; 2.2090x over previous
//
#include <hip/hip_runtime.h>

#define N_ENEMY 4000000
#define N_GUN   1000000
#define N_EDGES 16000000
#define OUTD    8

#define NB   1024      // dst buckets
#define GPB  977       // guns per bucket
#define T8   8192      // scatter tile
#define NT8  1954      // ceil(16M/8192)
#define EPT8 32

#define CH   4096      // bucket_v9 chunk
#define CEPT 16        // CH/256

// exact floor(dst/977) for dst <= 1M
__device__ __forceinline__ unsigned int bucket_of(unsigned int dst) {
    return (unsigned int)(((unsigned long long)dst * 1125395730ull) >> 40);
}
__device__ __forceinline__ unsigned int rne_bf16(unsigned int u) {
    return (u + 0x7FFFu + ((u >> 16) & 1u)) >> 16;
}

// ---- Fold W_l@W_fc (4x8), W_r@W_fc (8), b_l@W_fc + b_fc (8) into P[48] ----
__global__ void prep_params(const float* __restrict__ W_l, const float* __restrict__ b_l,
                            const float* __restrict__ W_r, const float* __restrict__ W_fc,
                            const float* __restrict__ b_fc, float* __restrict__ P) {
    int o = threadIdx.x;
    if (o < OUTD) {
        float a0 = 0.f, a1 = 0.f, a2 = 0.f, a3 = 0.f, r = 0.f, c = 0.f;
        for (int h = 0; h < 64; ++h) {
            float w = W_fc[h * OUTD + o];
            a0 += W_l[0 * 64 + h] * w;
            a1 += W_l[1 * 64 + h] * w;
            a2 += W_l[2 * 64 + h] * w;
            a3 += W_l[3 * 64 + h] * w;
            r  += W_r[h] * w;
            c  += b_l[h] * w;
        }
        P[0 * OUTD + o] = a0;
        P[1 * OUTD + o] = a1;
        P[2 * OUTD + o] = a2;
        P[3 * OUTD + o] = a3;
        P[4 * OUTD + o] = r;
        P[5 * OUTD + o] = c + b_fc[o];
    }
}

// ---- Convert x_enemy f32x4 -> bf16x4 (packed into uint2) ----
__global__ void conv_kernel(const uint4* __restrict__ xe, uint2* __restrict__ xeb) {
    int i = blockIdx.x * blockDim.x + threadIdx.x;
    if (i >= N_ENEMY) return;
    uint4 v = xe[i];
    uint2 q;
    q.x = rne_bf16(v.x) | (rne_bf16(v.y) << 16);
    q.y = rne_bf16(v.z) | (rne_bf16(v.w) << 16);
    xeb[i] = q;
}

// ---- per-tile dst-bucket histogram ----
__global__ void hist2_kernel(const int* __restrict__ edst, unsigned short* __restrict__ tileh) {
    __shared__ unsigned int lh[NB];
    int t = threadIdx.x;
    for (int i = t; i < NB; i += 256) lh[i] = 0;
    __syncthreads();
    int ebase = blockIdx.x * T8;
    int nE = N_EDGES - ebase;
    if (nE > T8) nE = T8;
    for (int i = t; i < nE; i += 256)
        atomicAdd(&lh[bucket_of((unsigned)edst[ebase + i])], 1u);
    __syncthreads();
    unsigned short* row = tileh + (size_t)blockIdx.x * NB;
    for (int i = t; i < NB; i += 256) row[i] = (unsigned short)lh[i];
}

// ---- per-bucket exclusive prefix over tiles (in-place) + totals ----
template<int K>
__global__ __launch_bounds__(256)
void tile_scanT(unsigned short* __restrict__ tileh, unsigned int* __restrict__ tot,
                int nbk, int ntile) {
    __shared__ unsigned int part[256][17];
    int t = threadIdx.x;
    int b0 = blockIdx.x * 16;
    unsigned int loc[16];
#pragma unroll
    for (int j = 0; j < 16; ++j) loc[j] = 0;
    for (int k = 0; k < K; ++k) {
        int tile = t * K + k;
        if (tile < ntile) {
            const unsigned short* row = tileh + (size_t)tile * nbk + b0;
#pragma unroll
            for (int j = 0; j < 16; ++j) loc[j] += row[j];
        }
    }
#pragma unroll
    for (int j = 0; j < 16; ++j) part[t][j] = loc[j];
    __syncthreads();
    if (t < 16) {
        unsigned int acc = 0;
        for (int i = 0; i < 256; ++i) {
            unsigned int v = part[i][t];
            part[i][t] = acc;
            acc += v;
        }
        tot[b0 + t] = acc;
    }
    __syncthreads();
    unsigned int run[16];
#pragma unroll
    for (int j = 0; j < 16; ++j) run[j] = part[t][j];
    for (int k = 0; k < K; ++k) {
        int tile = t * K + k;
        if (tile < ntile) {
            unsigned short* row = tileh + (size_t)tile * nbk + b0;
#pragma unroll
            for (int j = 0; j < 16; ++j) {
                unsigned int c = row[j];
                row[j] = (unsigned short)run[j];
                run[j] += c;
            }
        }
    }
}

__global__ void scan_kernel(const unsigned int* __restrict__ tot,
                            unsigned int* __restrict__ offsets) {
    __shared__ unsigned int tmp[1024];
    int t = threadIdx.x;
    unsigned int v0 = (t < NB) ? tot[t] : 0u;
    tmp[t] = v0;
    __syncthreads();
    for (int d = 1; d < 1024; d <<= 1) {
        unsigned int v = (t >= d) ? tmp[t - d] : 0u;
        __syncthreads();
        tmp[t] += v;
        __syncthreads();
    }
    if (t < NB) offsets[t] = tmp[t] - v0;
    if (t == NB - 1) offsets[NB] = tmp[t];
}

// ---- tile-sorted partition by dst bucket; payload = (src<<10)|g; no global atomics ----
__global__ __launch_bounds__(256, 2)
void scatter_sorted(const int* __restrict__ esrc, const int* __restrict__ edst,
                    const unsigned int* __restrict__ offsets,
                    const unsigned short* __restrict__ tileh,
                    unsigned int* __restrict__ payload) {
    __shared__ unsigned int cnt[NB];
    __shared__ unsigned int base[NB];
    __shared__ unsigned int gb[NB];
    __shared__ unsigned short bOf[T8];
    __shared__ unsigned int sorted[T8];
    __shared__ unsigned int partial[256];
    int t = threadIdx.x;
    int tile = blockIdx.x;
    int ebase = tile * T8;
    int nE = N_EDGES - ebase;
    if (nE > T8) nE = T8;
    for (int i = t; i < NB; i += 256) cnt[i] = 0;
    __syncthreads();
    unsigned int w[EPT8];
    unsigned int br[EPT8];
#pragma unroll
    for (int k = 0; k < EPT8; ++k) {
        int idx = k * 256 + t;
        if (idx < nE) {
            unsigned int s = (unsigned int)esrc[ebase + idx];
            unsigned int d = (unsigned int)edst[ebase + idx];
            unsigned int b = bucket_of(d);
            unsigned int g = d - b * GPB;
            unsigned int r = atomicAdd(&cnt[b], 1u);
            w[k]  = (s << 10) | g;
            br[k] = (b << 13) | r;
        } else br[k] = 0xFFFFFFFFu;
    }
    __syncthreads();
    unsigned int loc[4];
    unsigned int s = 0;
#pragma unroll
    for (int j = 0; j < 4; ++j) {
        int b = t * 4 + j;
        unsigned int c = cnt[b];
        loc[j] = s; s += c;
    }
    partial[t] = s;
    __syncthreads();
    for (int d = 1; d < 256; d <<= 1) {
        unsigned int v = (t >= d) ? partial[t - d] : 0u;
        __syncthreads();
        partial[t] += v;
        __syncthreads();
    }
    unsigned int excl = (t > 0) ? partial[t - 1] : 0u;
#pragma unroll
    for (int j = 0; j < 4; ++j) base[t * 4 + j] = excl + loc[j];
    __syncthreads();
    const unsigned short* trow = tileh + (size_t)tile * NB;
#pragma unroll
    for (int j = 0; j < 4; ++j) {
        int b = t * 4 + j;
        gb[b] = offsets[b] + (unsigned int)trow[b];
        unsigned int bs = base[b];
        unsigned int c = cnt[b];
        for (unsigned int p = bs; p < bs + c; ++p) bOf[p] = (unsigned short)b;
    }
    __syncthreads();
#pragma unroll
    for (int k = 0; k < EPT8; ++k) {
        if (br[k] != 0xFFFFFFFFu) {
            unsigned int b = br[k] >> 13;
            unsigned int r = br[k] & 8191u;
            sorted[base[b] + r] = w[k];
        }
    }
    __syncthreads();
    for (int p = t; p < nE; p += 256) {
        unsigned int b = bOf[p];
        payload[gb[b] + ((unsigned int)p - base[b])] = sorted[p];
    }
}

// ---- bucket_v9: 1 LDS atomic/edge (rank=hist), g-sorted LDS, register reduce ----
__global__ __launch_bounds__(256)
void bucket_v9(const unsigned int* __restrict__ offsets,
               const unsigned int* __restrict__ payload,
               const uint2* __restrict__ xeb,
               const float* __restrict__ xg,
               const float* __restrict__ P,
               float* __restrict__ out) {
    __shared__ unsigned long long sorted[CH];   // 32 KB
    __shared__ unsigned int cnt[1024];
    __shared__ unsigned int base_[1024];
    __shared__ unsigned int partial[256];
    __shared__ float sP[48];
    int t = threadIdx.x;
    if (t < 48) sP[t] = P[t];
    __syncthreads();

    // per-thread accumulators: guns t, 256+t, 512+t, 768+t
    float a0[4] = {0,0,0,0}, a1[4] = {0,0,0,0}, a2[4] = {0,0,0,0}, a3[4] = {0,0,0,0};
    float an[4] = {0,0,0,0};

    unsigned int b = blockIdx.x;
    unsigned int segS = offsets[b], segE = offsets[b + 1];

    for (unsigned int cs = segS; cs < segE; cs += CH) {
        int n = (int)((segE - cs < (unsigned int)CH) ? (segE - cs) : (unsigned int)CH);
        for (int i = t; i < 1024; i += 256) cnt[i] = 0;
        __syncthreads();

        unsigned int g_[CEPT], r_[CEPT];
        uint2 q_[CEPT];
#pragma unroll
        for (int k = 0; k < CEPT; ++k) {
            int idx = k * 256 + t;
            if (idx < n) {
                unsigned int p = payload[cs + idx];
                q_[k] = xeb[p >> 10];
                unsigned int g = p & 1023u;
                g_[k] = g;
                r_[k] = atomicAdd(&cnt[g], 1u);   // ONE atomic: rank AND hist
            } else g_[k] = 0xFFFFFFFFu;
        }
        __syncthreads();

        // prefix cnt -> base_
        unsigned int loc[4];
        unsigned int acc = 0;
#pragma unroll
        for (int j = 0; j < 4; ++j) {
            loc[j] = acc; acc += cnt[t * 4 + j];
        }
        partial[t] = acc;
        __syncthreads();
        for (int d = 1; d < 256; d <<= 1) {
            unsigned int v = (t >= d) ? partial[t - d] : 0u;
            __syncthreads();
            partial[t] += v;
            __syncthreads();
        }
        unsigned int excl = (t > 0) ? partial[t - 1] : 0u;
#pragma unroll
        for (int j = 0; j < 4; ++j) base_[t * 4 + j] = excl + loc[j];
        __syncthreads();

        // plain scatter write into g-sorted order
#pragma unroll
        for (int k = 0; k < CEPT; ++k) {
            if (g_[k] != 0xFFFFFFFFu) {
                sorted[base_[g_[k]] + r_[k]] =
                    ((unsigned long long)q_[k].y << 32) | (unsigned long long)q_[k].x;
            }
        }
        __syncthreads();

        // atomic-free register reduce over owned guns' contiguous runs
#pragma unroll
        for (int j = 0; j < 4; ++j) {
            int g = j * 256 + t;
            unsigned int bs = base_[g], c = cnt[g];
            for (unsigned int p2 = bs; p2 < bs + c; ++p2) {
                unsigned long long v = sorted[p2];
                unsigned int lo = (unsigned int)v, hi = (unsigned int)(v >> 32);
                a0[j] += __uint_as_float(lo << 16);
                a1[j] += __uint_as_float(lo & 0xffff0000u);
                a2[j] += __uint_as_float(hi << 16);
                a3[j] += __uint_as_float(hi & 0xffff0000u);
            }
            an[j] += (float)c;
        }
        __syncthreads();
    }

    // epilogue: non-atomic, direct to out
#pragma unroll
    for (int j = 0; j < 4; ++j) {
        int g = j * 256 + t;
        if (g >= GPB) continue;
        unsigned int G = b * GPB + (unsigned int)g;
        if (G >= N_GUN) continue;
        float inv = 1.0f / fmaxf(an[j], 1.0f);
        float m0 = a0[j] * inv, m1 = a1[j] * inv, m2 = a2[j] * inv, m3 = a3[j] * inv;
        float xv = xg[G];
        float res[OUTD];
#pragma unroll
        for (int o = 0; o < OUTD; ++o) {
            res[o] = m0 * sP[o] + m1 * sP[8 + o] + m2 * sP[16 + o] + m3 * sP[24 + o]
                   + xv * sP[32 + o] + sP[40 + o];
        }
        float4* op = (float4*)(out + (size_t)G * OUTD);
        op[0] = make_float4(res[0], res[1], res[2], res[3]);
        op[1] = make_float4(res[4], res[5], res[6], res[7]);
    }
}

// ================= atomic fallback (tiny ws) =================================
__global__ void edge_kernel(const int4* __restrict__ esrc4, const int4* __restrict__ edst4,
                            const float4* __restrict__ xe, float* __restrict__ summed,
                            float* __restrict__ counts) {
    int t = blockIdx.x * blockDim.x + threadIdx.x;
    if (t >= N_EDGES / 4) return;
    int4 s4 = esrc4[t];
    int4 d4 = edst4[t];
    int ss[4] = { s4.x, s4.y, s4.z, s4.w };
    int dd[4] = { d4.x, d4.y, d4.z, d4.w };
#pragma unroll
    for (int k = 0; k < 4; ++k) {
        float4 m = xe[ss[k]];
        float* basep = summed + (size_t)dd[k] * 4;
        atomicAdd(basep + 0, m.x);
        atomicAdd(basep + 1, m.y);
        atomicAdd(basep + 2, m.z);
        atomicAdd(basep + 3, m.w);
        atomicAdd(counts + dd[k], 1.0f);
    }
}

__global__ void gun_kernel(const float4* __restrict__ summed, const float* __restrict__ counts,
                           const float* __restrict__ xg, const float* __restrict__ P,
                           float* __restrict__ out) {
    __shared__ float sP[48];
    if (threadIdx.x < 48) sP[threadIdx.x] = P[threadIdx.x];
    __syncthreads();
    int g = blockIdx.x * blockDim.x + threadIdx.x;
    if (g >= N_GUN) return;
    float4 s = summed[g];
    float cnt = counts[g];
    float inv = 1.0f / fmaxf(cnt, 1.0f);
    float m0 = s.x * inv, m1 = s.y * inv, m2 = s.z * inv, m3 = s.w * inv;
    float xv = xg[g];
    float res[OUTD];
#pragma unroll
    for (int o = 0; o < OUTD; ++o) {
        res[o] = m0 * sP[o] + m1 * sP[8 + o] + m2 * sP[16 + o] + m3 * sP[24 + o]
               + xv * sP[32 + o] + sP[40 + o];
    }
    float4* op = (float4*)(out + (size_t)g * OUTD);
    op[0] = make_float4(res[0], res[1], res[2], res[3]);
    op[1] = make_float4(res[4], res[5], res[6], res[7]);
}

extern "C" void kernel_launch(void* const* d_in, const int* in_sizes, int n_in,
                              void* d_out, int out_size, void* d_ws, size_t ws_size,
                              hipStream_t stream) {
    const float* x_enemy = (const float*)d_in[0];
    const float* x_gun   = (const float*)d_in[1];
    const int*   esrc    = (const int*)d_in[2];
    const int*   edst    = (const int*)d_in[3];
    const float* W_l     = (const float*)d_in[4];
    const float* b_l     = (const float*)d_in[5];
    const float* W_r     = (const float*)d_in[6];
    const float* W_fc    = (const float*)d_in[7];
    const float* b_fc    = (const float*)d_in[8];
    float* out = (float*)d_out;

    // ws layout (u32 units). tileh (u16, 4MB) aliases the xeb region: tileh is
    // consumed by scatter_sorted; conv_kernel (writing xeb) runs after it.
    const size_t PAYLOAD_OFF = 0;                            // 16M u32 = 64 MB
    const size_t XEB_OFF     = (size_t)N_EDGES;              // 8M u32 = 32 MB
    const size_t TOT_OFF     = XEB_OFF + (size_t)N_ENEMY*2;  // +1024
    const size_t OFFS_OFF    = TOT_OFF + NB;                 // +1025
    const size_t P_OFF       = OFFS_OFF + NB + 1;            // +48
    const size_t NEEDED_FULL = (P_OFF + 64) * sizeof(unsigned int);

    if (ws_size >= NEEDED_FULL) {
        unsigned int*   ws      = (unsigned int*)d_ws;
        unsigned int*   payload = ws + PAYLOAD_OFF;
        uint2*          xeb     = (uint2*)(ws + XEB_OFF);
        unsigned short* tileh   = (unsigned short*)(ws + XEB_OFF);  // alias, dead before conv
        unsigned int*   tot     = ws + TOT_OFF;
        unsigned int*   offsets = ws + OFFS_OFF;
        float*          P       = (float*)(ws + P_OFF);

        prep_params<<<1, 64, 0, stream>>>(W_l, b_l, W_r, W_fc, b_fc, P);
        hist2_kernel<<<NT8, 256, 0, stream>>>(edst, tileh);
        tile_scanT<8><<<NB / 16, 256, 0, stream>>>(tileh, tot, NB, NT8);
        scan_kernel<<<1, 1024, 0, stream>>>(tot, offsets);
        scatter_sorted<<<NT8, 256, 0, stream>>>(esrc, edst, offsets, tileh, payload);
        conv_kernel<<<(N_ENEMY + 255) / 256, 256, 0, stream>>>((const uint4*)x_enemy, xeb);
        bucket_v9<<<NB, 256, 0, stream>>>(offsets, payload, xeb, x_gun, P, out);
    } else {
        float* summed = (float*)d_ws;
        float* counts = summed + (size_t)N_GUN * 4;
        float* P      = counts + N_GUN;
        hipMemsetAsync(d_ws, 0, ((size_t)N_GUN * 5 + 48) * sizeof(float), stream);
        prep_params<<<1, 64, 0, stream>>>(W_l, b_l, W_r, W_fc, b_fc, P);
        int edge_threads = N_EDGES / 4;
        edge_kernel<<<(edge_threads + 255) / 256, 256, 0, stream>>>(
            (const int4*)esrc, (const int4*)edst, (const float4*)x_enemy, summed, counts);
        gun_kernel<<<(N_GUN + 255) / 256, 256, 0, stream>>>(
            (const float4*)summed, counts, x_gun, P, out);
    }
}

// Round 13
// 413.483 us; speedup vs baseline: 2.4592x; 1.1133x over previous
//
#include <hip/hip_runtime.h>

#define N_ENEMY 4000000
#define N_GUN   1000000
#define N_EDGES 16000000
#define OUTD    8

#define NB   1024      // dst buckets
#define GPB  977       // guns per bucket
#define T8   8192      // scatter tile
#define NT8  1954      // ceil(16M/8192)
#define EPT8 32

#define CH   4096      // bucket_v9 chunk
#define CEPT 16        // CH/256

#define NS   8         // src slices: 512K enemies = 4MB bf16 = one XCD L2
#define SEG_CAP 16128  // slice_sort LDS capacity

// exact floor(dst/977) for dst <= 1M
__device__ __forceinline__ unsigned int bucket_of(unsigned int dst) {
    return (unsigned int)(((unsigned long long)dst * 1125395730ull) >> 40);
}
__device__ __forceinline__ unsigned int rne_bf16(unsigned int u) {
    return (u + 0x7FFFu + ((u >> 16) & 1u)) >> 16;
}
__device__ __forceinline__ unsigned int get_xcc() {
    unsigned int x;
    asm("s_getreg_b32 %0, hwreg(HW_REG_XCC_ID)" : "=s"(x));
    return x;
}

// ---- Fold W_l@W_fc (4x8), W_r@W_fc (8), b_l@W_fc + b_fc (8) into P[48] ----
__global__ void prep_params(const float* __restrict__ W_l, const float* __restrict__ b_l,
                            const float* __restrict__ W_r, const float* __restrict__ W_fc,
                            const float* __restrict__ b_fc, float* __restrict__ P) {
    int o = threadIdx.x;
    if (o < OUTD) {
        float a0 = 0.f, a1 = 0.f, a2 = 0.f, a3 = 0.f, r = 0.f, c = 0.f;
        for (int h = 0; h < 64; ++h) {
            float w = W_fc[h * OUTD + o];
            a0 += W_l[0 * 64 + h] * w;
            a1 += W_l[1 * 64 + h] * w;
            a2 += W_l[2 * 64 + h] * w;
            a3 += W_l[3 * 64 + h] * w;
            r  += W_r[h] * w;
            c  += b_l[h] * w;
        }
        P[0 * OUTD + o] = a0;
        P[1 * OUTD + o] = a1;
        P[2 * OUTD + o] = a2;
        P[3 * OUTD + o] = a3;
        P[4 * OUTD + o] = r;
        P[5 * OUTD + o] = c + b_fc[o];
    }
}

// ---- Convert x_enemy f32x4 -> bf16x4 (packed into uint2) ----
__global__ void conv_kernel(const uint4* __restrict__ xe, uint2* __restrict__ xeb) {
    int i = blockIdx.x * blockDim.x + threadIdx.x;
    if (i >= N_ENEMY) return;
    uint4 v = xe[i];
    uint2 q;
    q.x = rne_bf16(v.x) | (rne_bf16(v.y) << 16);
    q.y = rne_bf16(v.z) | (rne_bf16(v.w) << 16);
    xeb[i] = q;
}

// ---- per-tile dst-bucket histogram ----
__global__ void hist2_kernel(const int* __restrict__ edst, unsigned short* __restrict__ tileh) {
    __shared__ unsigned int lh[NB];
    int t = threadIdx.x;
    for (int i = t; i < NB; i += 256) lh[i] = 0;
    __syncthreads();
    int ebase = blockIdx.x * T8;
    int nE = N_EDGES - ebase;
    if (nE > T8) nE = T8;
    for (int i = t; i < nE; i += 256)
        atomicAdd(&lh[bucket_of((unsigned)edst[ebase + i])], 1u);
    __syncthreads();
    unsigned short* row = tileh + (size_t)blockIdx.x * NB;
    for (int i = t; i < NB; i += 256) row[i] = (unsigned short)lh[i];
}

// ---- per-bucket exclusive prefix over tiles (in-place) + totals ----
template<int K>
__global__ __launch_bounds__(256)
void tile_scanT(unsigned short* __restrict__ tileh, unsigned int* __restrict__ tot,
                int nbk, int ntile) {
    __shared__ unsigned int part[256][17];
    int t = threadIdx.x;
    int b0 = blockIdx.x * 16;
    unsigned int loc[16];
#pragma unroll
    for (int j = 0; j < 16; ++j) loc[j] = 0;
    for (int k = 0; k < K; ++k) {
        int tile = t * K + k;
        if (tile < ntile) {
            const unsigned short* row = tileh + (size_t)tile * nbk + b0;
#pragma unroll
            for (int j = 0; j < 16; ++j) loc[j] += row[j];
        }
    }
#pragma unroll
    for (int j = 0; j < 16; ++j) part[t][j] = loc[j];
    __syncthreads();
    if (t < 16) {
        unsigned int acc = 0;
        for (int i = 0; i < 256; ++i) {
            unsigned int v = part[i][t];
            part[i][t] = acc;
            acc += v;
        }
        tot[b0 + t] = acc;
    }
    __syncthreads();
    unsigned int run[16];
#pragma unroll
    for (int j = 0; j < 16; ++j) run[j] = part[t][j];
    for (int k = 0; k < K; ++k) {
        int tile = t * K + k;
        if (tile < ntile) {
            unsigned short* row = tileh + (size_t)tile * nbk + b0;
#pragma unroll
            for (int j = 0; j < 16; ++j) {
                unsigned int c = row[j];
                row[j] = (unsigned short)run[j];
                run[j] += c;
            }
        }
    }
}

__global__ void scan_kernel(const unsigned int* __restrict__ tot,
                            unsigned int* __restrict__ offsets) {
    __shared__ unsigned int tmp[1024];
    int t = threadIdx.x;
    unsigned int v0 = (t < NB) ? tot[t] : 0u;
    tmp[t] = v0;
    __syncthreads();
    for (int d = 1; d < 1024; d <<= 1) {
        unsigned int v = (t >= d) ? tmp[t - d] : 0u;
        __syncthreads();
        tmp[t] += v;
        __syncthreads();
    }
    if (t < NB) offsets[t] = tmp[t] - v0;
    if (t == NB - 1) offsets[NB] = tmp[t];
}

// ---- tile-sorted partition by dst bucket; payload = (src<<10)|g; no global atomics ----
__global__ __launch_bounds__(256, 2)
void scatter_sorted(const int* __restrict__ esrc, const int* __restrict__ edst,
                    const unsigned int* __restrict__ offsets,
                    const unsigned short* __restrict__ tileh,
                    unsigned int* __restrict__ payload) {
    __shared__ unsigned int cnt[NB];
    __shared__ unsigned int base[NB];
    __shared__ unsigned int gb[NB];
    __shared__ unsigned short bOf[T8];
    __shared__ unsigned int sorted[T8];
    __shared__ unsigned int partial[256];
    int t = threadIdx.x;
    int tile = blockIdx.x;
    int ebase = tile * T8;
    int nE = N_EDGES - ebase;
    if (nE > T8) nE = T8;
    for (int i = t; i < NB; i += 256) cnt[i] = 0;
    __syncthreads();
    unsigned int w[EPT8];
    unsigned int br[EPT8];
#pragma unroll
    for (int k = 0; k < EPT8; ++k) {
        int idx = k * 256 + t;
        if (idx < nE) {
            unsigned int s = (unsigned int)esrc[ebase + idx];
            unsigned int d = (unsigned int)edst[ebase + idx];
            unsigned int b = bucket_of(d);
            unsigned int g = d - b * GPB;
            unsigned int r = atomicAdd(&cnt[b], 1u);
            w[k]  = (s << 10) | g;
            br[k] = (b << 13) | r;
        } else br[k] = 0xFFFFFFFFu;
    }
    __syncthreads();
    unsigned int loc[4];
    unsigned int s = 0;
#pragma unroll
    for (int j = 0; j < 4; ++j) {
        int b = t * 4 + j;
        unsigned int c = cnt[b];
        loc[j] = s; s += c;
    }
    partial[t] = s;
    __syncthreads();
    for (int d = 1; d < 256; d <<= 1) {
        unsigned int v = (t >= d) ? partial[t - d] : 0u;
        __syncthreads();
        partial[t] += v;
        __syncthreads();
    }
    unsigned int excl = (t > 0) ? partial[t - 1] : 0u;
#pragma unroll
    for (int j = 0; j < 4; ++j) base[t * 4 + j] = excl + loc[j];
    __syncthreads();
    const unsigned short* trow = tileh + (size_t)tile * NB;
#pragma unroll
    for (int j = 0; j < 4; ++j) {
        int b = t * 4 + j;
        gb[b] = offsets[b] + (unsigned int)trow[b];
        unsigned int bs = base[b];
        unsigned int c = cnt[b];
        for (unsigned int p = bs; p < bs + c; ++p) bOf[p] = (unsigned short)b;
    }
    __syncthreads();
#pragma unroll
    for (int k = 0; k < EPT8; ++k) {
        if (br[k] != 0xFFFFFFFFu) {
            unsigned int b = br[k] >> 13;
            unsigned int r = br[k] & 8191u;
            sorted[base[b] + r] = w[k];
        }
    }
    __syncthreads();
    for (int p = t; p < nE; p += 256) {
        unsigned int b = bOf[p];
        payload[gb[b] + ((unsigned int)p - base[b])] = sorted[p];
    }
}

// ---- per-bucket counting sort by src-slice (slice = w>>29 since src=w>>10, 8 slices) ----
// stab[b][k] (k=0..NS): absolute run starts; stab[b][NS] = segment end.
__global__ __launch_bounds__(256)
void slice_sort(const unsigned int* __restrict__ offsets,
                unsigned int* __restrict__ payload,
                unsigned int* __restrict__ stab) {
    __shared__ unsigned int A[SEG_CAP];
    __shared__ unsigned int cnt[NS];
    __shared__ unsigned int base[NS + 1];
    int b = blockIdx.x;
    int t = threadIdx.x;
    unsigned int segS = offsets[b];
    unsigned int segE = offsets[b + 1];
    unsigned int len = segE - segS;
    if (len > SEG_CAP) {
        if (t <= NS) stab[b * (NS + 1) + t] = (t == 0) ? segS : segE;
        return;
    }
    if (t < NS) cnt[t] = 0;
    __syncthreads();
    for (unsigned int i = t; i < len; i += 256) {
        unsigned int w = payload[segS + i];
        A[i] = w;
        atomicAdd(&cnt[w >> 29], 1u);
    }
    __syncthreads();
    if (t == 0) {
        unsigned int acc = 0;
        for (int k = 0; k < NS; ++k) { base[k] = acc; acc += cnt[k]; }
        base[NS] = acc;
    }
    __syncthreads();
    if (t < NS) cnt[t] = 0;
    __syncthreads();
    for (unsigned int i = t; i < len; i += 256) {
        unsigned int w = A[i];
        unsigned int k = w >> 29;
        unsigned int r = atomicAdd(&cnt[k], 1u);
        payload[segS + base[k] + r] = w;
    }
    if (t <= NS) stab[b * (NS + 1) + t] = segS + base[t];
}

// ---- bucket_v9: slice-rotated walk, 1 LDS atomic/edge, g-sorted LDS, reg reduce ----
__global__ __launch_bounds__(256)
void bucket_v9(const unsigned int* __restrict__ stab,
               const unsigned int* __restrict__ payload,
               const uint2* __restrict__ xeb,
               const float* __restrict__ xg,
               const float* __restrict__ P,
               float* __restrict__ out) {
    __shared__ unsigned long long sorted[CH];   // 32 KB
    __shared__ unsigned int cnt[1024];
    __shared__ unsigned int base_[1024];
    __shared__ unsigned int partial[256];
    __shared__ float sP[48];
    int t = threadIdx.x;
    if (t < 48) sP[t] = P[t];
    __syncthreads();

    float a0[4] = {0,0,0,0}, a1[4] = {0,0,0,0}, a2[4] = {0,0,0,0}, a3[4] = {0,0,0,0};
    float an[4] = {0,0,0,0};

    unsigned int b = blockIdx.x;
    unsigned int rot = get_xcc() & (NS - 1u);   // order-only; correctness xcc-independent

    for (int si = 0; si < NS; ++si) {
        unsigned int s = ((unsigned int)si + rot) & (NS - 1u);
        unsigned int rs = stab[b * (NS + 1) + s];
        unsigned int re = stab[b * (NS + 1) + s + 1];

        for (unsigned int cs = rs; cs < re; cs += CH) {
            int n = (int)((re - cs < (unsigned int)CH) ? (re - cs) : (unsigned int)CH);
            for (int i = t; i < 1024; i += 256) cnt[i] = 0;
            __syncthreads();

            unsigned int g_[CEPT], r_[CEPT];
            uint2 q_[CEPT];
#pragma unroll
            for (int k = 0; k < CEPT; ++k) {
                int idx = k * 256 + t;
                if (idx < n) {
                    unsigned int p = payload[cs + idx];
                    q_[k] = xeb[p >> 10];
                    unsigned int g = p & 1023u;
                    g_[k] = g;
                    r_[k] = atomicAdd(&cnt[g], 1u);   // ONE atomic: rank AND hist
                } else g_[k] = 0xFFFFFFFFu;
            }
            __syncthreads();

            unsigned int loc[4];
            unsigned int acc = 0;
#pragma unroll
            for (int j = 0; j < 4; ++j) {
                loc[j] = acc; acc += cnt[t * 4 + j];
            }
            partial[t] = acc;
            __syncthreads();
            for (int d = 1; d < 256; d <<= 1) {
                unsigned int v = (t >= d) ? partial[t - d] : 0u;
                __syncthreads();
                partial[t] += v;
                __syncthreads();
            }
            unsigned int excl = (t > 0) ? partial[t - 1] : 0u;
#pragma unroll
            for (int j = 0; j < 4; ++j) base_[t * 4 + j] = excl + loc[j];
            __syncthreads();

#pragma unroll
            for (int k = 0; k < CEPT; ++k) {
                if (g_[k] != 0xFFFFFFFFu) {
                    sorted[base_[g_[k]] + r_[k]] =
                        ((unsigned long long)q_[k].y << 32) | (unsigned long long)q_[k].x;
                }
            }
            __syncthreads();

#pragma unroll
            for (int j = 0; j < 4; ++j) {
                int g = j * 256 + t;
                unsigned int bs = base_[g], c = cnt[g];
                for (unsigned int p2 = bs; p2 < bs + c; ++p2) {
                    unsigned long long v = sorted[p2];
                    unsigned int lo = (unsigned int)v, hi = (unsigned int)(v >> 32);
                    a0[j] += __uint_as_float(lo << 16);
                    a1[j] += __uint_as_float(lo & 0xffff0000u);
                    a2[j] += __uint_as_float(hi << 16);
                    a3[j] += __uint_as_float(hi & 0xffff0000u);
                }
                an[j] += (float)c;
            }
            __syncthreads();
        }
    }

#pragma unroll
    for (int j = 0; j < 4; ++j) {
        int g = j * 256 + t;
        if (g >= GPB) continue;
        unsigned int G = b * GPB + (unsigned int)g;
        if (G >= N_GUN) continue;
        float inv = 1.0f / fmaxf(an[j], 1.0f);
        float m0 = a0[j] * inv, m1 = a1[j] * inv, m2 = a2[j] * inv, m3 = a3[j] * inv;
        float xv = xg[G];
        float res[OUTD];
#pragma unroll
        for (int o = 0; o < OUTD; ++o) {
            res[o] = m0 * sP[o] + m1 * sP[8 + o] + m2 * sP[16 + o] + m3 * sP[24 + o]
                   + xv * sP[32 + o] + sP[40 + o];
        }
        float4* op = (float4*)(out + (size_t)G * OUTD);
        op[0] = make_float4(res[0], res[1], res[2], res[3]);
        op[1] = make_float4(res[4], res[5], res[6], res[7]);
    }
}

// ================= atomic fallback (tiny ws) =================================
__global__ void edge_kernel(const int4* __restrict__ esrc4, const int4* __restrict__ edst4,
                            const float4* __restrict__ xe, float* __restrict__ summed,
                            float* __restrict__ counts) {
    int t = blockIdx.x * blockDim.x + threadIdx.x;
    if (t >= N_EDGES / 4) return;
    int4 s4 = esrc4[t];
    int4 d4 = edst4[t];
    int ss[4] = { s4.x, s4.y, s4.z, s4.w };
    int dd[4] = { d4.x, d4.y, d4.z, d4.w };
#pragma unroll
    for (int k = 0; k < 4; ++k) {
        float4 m = xe[ss[k]];
        float* basep = summed + (size_t)dd[k] * 4;
        atomicAdd(basep + 0, m.x);
        atomicAdd(basep + 1, m.y);
        atomicAdd(basep + 2, m.z);
        atomicAdd(basep + 3, m.w);
        atomicAdd(counts + dd[k], 1.0f);
    }
}

__global__ void gun_kernel(const float4* __restrict__ summed, const float* __restrict__ counts,
                           const float* __restrict__ xg, const float* __restrict__ P,
                           float* __restrict__ out) {
    __shared__ float sP[48];
    if (threadIdx.x < 48) sP[threadIdx.x] = P[threadIdx.x];
    __syncthreads();
    int g = blockIdx.x * blockDim.x + threadIdx.x;
    if (g >= N_GUN) return;
    float4 s = summed[g];
    float cnt = counts[g];
    float inv = 1.0f / fmaxf(cnt, 1.0f);
    float m0 = s.x * inv, m1 = s.y * inv, m2 = s.z * inv, m3 = s.w * inv;
    float xv = xg[g];
    float res[OUTD];
#pragma unroll
    for (int o = 0; o < OUTD; ++o) {
        res[o] = m0 * sP[o] + m1 * sP[8 + o] + m2 * sP[16 + o] + m3 * sP[24 + o]
               + xv * sP[32 + o] + sP[40 + o];
    }
    float4* op = (float4*)(out + (size_t)g * OUTD);
    op[0] = make_float4(res[0], res[1], res[2], res[3]);
    op[1] = make_float4(res[4], res[5], res[6], res[7]);
}

extern "C" void kernel_launch(void* const* d_in, const int* in_sizes, int n_in,
                              void* d_out, int out_size, void* d_ws, size_t ws_size,
                              hipStream_t stream) {
    const float* x_enemy = (const float*)d_in[0];
    const float* x_gun   = (const float*)d_in[1];
    const int*   esrc    = (const int*)d_in[2];
    const int*   edst    = (const int*)d_in[3];
    const float* W_l     = (const float*)d_in[4];
    const float* b_l     = (const float*)d_in[5];
    const float* W_r     = (const float*)d_in[6];
    const float* W_fc    = (const float*)d_in[7];
    const float* b_fc    = (const float*)d_in[8];
    float* out = (float*)d_out;

    // ws layout (u32 units). tileh (u16, 4MB) aliases the xeb region: tileh is
    // consumed by scatter_sorted; conv_kernel (writing xeb) runs after slice_sort.
    const size_t PAYLOAD_OFF = 0;                            // 16M u32 = 64 MB
    const size_t XEB_OFF     = (size_t)N_EDGES;              // 8M u32 = 32 MB
    const size_t TOT_OFF     = XEB_OFF + (size_t)N_ENEMY*2;  // +1024
    const size_t OFFS_OFF    = TOT_OFF + NB;                 // +1025
    const size_t P_OFF       = OFFS_OFF + NB + 1;            // +48
    const size_t STAB_OFF    = P_OFF + 48;                   // +NB*(NS+1)
    const size_t NEEDED_FULL = (STAB_OFF + (size_t)NB * (NS + 1) + 16) * sizeof(unsigned int);

    if (ws_size >= NEEDED_FULL) {
        unsigned int*   ws      = (unsigned int*)d_ws;
        unsigned int*   payload = ws + PAYLOAD_OFF;
        uint2*          xeb     = (uint2*)(ws + XEB_OFF);
        unsigned short* tileh   = (unsigned short*)(ws + XEB_OFF);  // alias, dead before conv
        unsigned int*   tot     = ws + TOT_OFF;
        unsigned int*   offsets = ws + OFFS_OFF;
        float*          P       = (float*)(ws + P_OFF);
        unsigned int*   stab    = ws + STAB_OFF;

        prep_params<<<1, 64, 0, stream>>>(W_l, b_l, W_r, W_fc, b_fc, P);
        hist2_kernel<<<NT8, 256, 0, stream>>>(edst, tileh);
        tile_scanT<8><<<NB / 16, 256, 0, stream>>>(tileh, tot, NB, NT8);
        scan_kernel<<<1, 1024, 0, stream>>>(tot, offsets);
        scatter_sorted<<<NT8, 256, 0, stream>>>(esrc, edst, offsets, tileh, payload);
        slice_sort<<<NB, 256, 0, stream>>>(offsets, payload, stab);
        conv_kernel<<<(N_ENEMY + 255) / 256, 256, 0, stream>>>((const uint4*)x_enemy, xeb);
        bucket_v9<<<NB, 256, 0, stream>>>(stab, payload, xeb, x_gun, P, out);
    } else {
        float* summed = (float*)d_ws;
        float* counts = summed + (size_t)N_GUN * 4;
        float* P      = counts + N_GUN;
        hipMemsetAsync(d_ws, 0, ((size_t)N_GUN * 5 + 48) * sizeof(float), stream);
        prep_params<<<1, 64, 0, stream>>>(W_l, b_l, W_r, W_fc, b_fc, P);
        int edge_threads = N_EDGES / 4;
        edge_kernel<<<(edge_threads + 255) / 256, 256, 0, stream>>>(
            (const int4*)esrc, (const int4*)edst, (const float4*)x_enemy, summed, counts);
        gun_kernel<<<(N_GUN + 255) / 256, 256, 0, stream>>>(
            (const float4*)summed, counts, x_gun, P, out);
    }
}